// Round 5
// baseline (370.700 us; speedup 1.0000x reference)
//
#include <hip/hip_runtime.h>
#include <hip/hip_bf16.h>

typedef __attribute__((ext_vector_type(8))) short short8;
typedef __attribute__((ext_vector_type(4))) short short4v;
typedef __attribute__((ext_vector_type(4))) float f32x4;

#define MFMA16(a, b, c) __builtin_amdgcn_mfma_f32_16x16x32_bf16(a, b, c, 0, 0, 0)

__device__ __forceinline__ unsigned short f2bf(float f) {
    union { __hip_bfloat16 h; unsigned short u; } v;
    v.h = __float2bfloat16(f);
    return v.u;
}

__device__ __forceinline__ short8 pack8(float4 a, float4 b) {
    short8 p;
    p[0] = (short)f2bf(a.x); p[1] = (short)f2bf(a.y);
    p[2] = (short)f2bf(a.z); p[3] = (short)f2bf(a.w);
    p[4] = (short)f2bf(b.x); p[5] = (short)f2bf(b.y);
    p[6] = (short)f2bf(b.z); p[7] = (short)f2bf(b.w);
    return p;
}

// XOR-swizzled LDS indexing (T2): linear rows, byte ^= (row&7)<<4.
__device__ __forceinline__ int swz64(int row, int bytecol) {   // 64-short rows
    return row * 64 + ((bytecol ^ ((row & 7) << 4)) >> 1);
}
__device__ __forceinline__ int swz256(int row, int bytecol) {  // 256-short rows
    return row * 256 + ((bytecol ^ ((row & 7) << 4)) >> 1);
}

// ---------------------------------------------------------------------------
// Weight prep: wt[m][n][k] = W_m[k][n] as bf16, m in {Wq,Wk,Wv,Wo}.
// ---------------------------------------------------------------------------
__global__ __launch_bounds__(256) void wprep(
    const float* __restrict__ Wq, const float* __restrict__ Wk,
    const float* __restrict__ Wv, const float* __restrict__ Wo,
    unsigned short* __restrict__ wt)
{
    __shared__ float tile[64][65];
    const int bid = blockIdx.x;
    const int m = bid >> 6, tb = bid & 63;
    const int kr = (tb >> 3) << 6, nc = (tb & 7) << 6;
    const float* W = (m == 0) ? Wq : (m == 1) ? Wk : (m == 2) ? Wv : Wo;
    const int tid = threadIdx.x;
    for (int i = tid; i < 4096; i += 256)
        tile[i >> 6][i & 63] = W[(size_t)(kr + (i >> 6)) * 512 + nc + (i & 63)];
    __syncthreads();
    unsigned short* dst = wt + (size_t)m * 262144;
    for (int i = tid; i < 4096; i += 256)
        dst[(size_t)(nc + (i >> 6)) * 512 + kr + (i & 63)] = f2bf(tile[i & 63][i >> 6]);
}

// ---------------------------------------------------------------------------
// QKV GEMM: qkvb[mat][t*8+h][i][d] (bf16) = X[65536x512] @ W_mat.
// Block tile 128 rows x 512 cols (one mat per block), BK=32, 1024 thr,
// 16 waves (4x4), wave tile 32x128. Register-prefetched staging.
// bid remap: the 3 N-blocks sharing an A-tile are adjacent on one XCD.
// ---------------------------------------------------------------------------
__global__ __launch_bounds__(1024, 4) void qkv_gemm(
    const float* __restrict__ hs,            // [65536][512] f32
    const unsigned short* __restrict__ wt,   // [4][512][512] bf16 W^T
    unsigned short* __restrict__ qkvb)       // [3][2048][256][64] bf16
{
    __shared__ unsigned short As[128 * 40];
    __shared__ unsigned short Bts[512 * 40];

    const int orig = blockIdx.x;             // 1536
    const int wg = (orig & 7) * 192 + (orig >> 3);
    const int mb = wg / 3;
    const int nb = wg - mb * 3;

    const int tid  = threadIdx.x;
    const int lane = tid & 63;
    const int w    = tid >> 6;
    const int l15  = lane & 15;
    const int hi4  = lane >> 4;
    const int wr   = w >> 2, wc = w & 3;

    f32x4 acc[2][8];
    #pragma unroll
    for (int m = 0; m < 2; ++m)
        #pragma unroll
        for (int n = 0; n < 8; ++n)
            acc[m][n] = (f32x4){0.f, 0.f, 0.f, 0.f};

    const bool isA = tid < 512;
    const int bn = tid & 511;
    const int ai = bn >> 2, aq = bn & 3;

    const float* __restrict__ asrc = hs + ((size_t)mb * 128 + ai) * 512 + aq * 8;
    const unsigned short* __restrict__ bsrc = wt + ((size_t)nb * 512 + bn) * 512;

    float4 af0, af1;
    short8 b8[4];
    if (isA) {
        af0 = *(const float4*)asrc; af1 = *(const float4*)(asrc + 4);
    } else {
        #pragma unroll
        for (int q = 0; q < 4; ++q) b8[q] = *(const short8*)(bsrc + q * 8);
    }

    for (int kb = 0; kb < 512; kb += 32) {
        if (isA) *(short8*)&As[ai * 40 + aq * 8] = pack8(af0, af1);
        else {
            #pragma unroll
            for (int q = 0; q < 4; ++q) *(short8*)&Bts[bn * 40 + q * 8] = b8[q];
        }
        __syncthreads();
        if (kb < 480) {
            const int kn = kb + 32;
            if (isA) {
                af0 = *(const float4*)(asrc + kn);
                af1 = *(const float4*)(asrc + kn + 4);
            } else {
                #pragma unroll
                for (int q = 0; q < 4; ++q)
                    b8[q] = *(const short8*)(bsrc + kn + q * 8);
            }
        }
        short8 afr[2];
        #pragma unroll
        for (int m = 0; m < 2; ++m)
            afr[m] = *(const short8*)&As[(wr * 32 + m * 16 + l15) * 40 + hi4 * 8];
        __builtin_amdgcn_s_setprio(1);
        #pragma unroll
        for (int n = 0; n < 8; ++n) {
            const short8 bfr = *(const short8*)&Bts[(wc * 128 + n * 16 + l15) * 40 + hi4 * 8];
            #pragma unroll
            for (int m = 0; m < 2; ++m)
                acc[m][n] = MFMA16(afr[m], bfr, acc[m][n]);
        }
        __builtin_amdgcn_s_setprio(0);
        __syncthreads();
    }

    // epilogue: bf16 scatter into [mat][t*8+h][i][d]
    const size_t matoff = (size_t)nb * 33554432;
    #pragma unroll
    for (int m = 0; m < 2; ++m) {
        #pragma unroll
        for (int n = 0; n < 8; ++n) {
            const int col = wc * 128 + n * 16 + l15;
            const int hh = col >> 6, d = col & 63;
            #pragma unroll
            for (int r = 0; r < 4; ++r) {
                const int row = mb * 128 + wr * 32 + m * 16 + hi4 * 4 + r;
                const int t = row >> 8, i = row & 255;
                qkvb[matoff + (((size_t)t * 8 + hh) << 14) + (i << 6) + d] =
                    f2bf(acc[m][n][r]);
            }
        }
    }
}

// ---------------------------------------------------------------------------
// Attention: one block per (t,h). Stage K (swizzled) + V (transpose->Vt) from
// qkvb; Q fragments straight to registers. 1024 thr = 16 waves, wave = 16 rows.
// Group-restricted flash over the contiguous group range.
// ---------------------------------------------------------------------------
__global__ __launch_bounds__(1024, 4) void attn_split(
    const unsigned short* __restrict__ qkvb,
    const int* __restrict__ gid,
    float* __restrict__ out)                 // [256][256][512] f32
{
    __shared__ unsigned short Ksh[256 * 64];
    __shared__ unsigned short Vt[64 * 256];
    __shared__ unsigned short Ps[256 * 64];  // V-transit, then P tiles
    __shared__ int sgid[256];
    __shared__ int glo[16], ghi[16];

    const int th = blockIdx.x;               // t*8+h
    const int t = th >> 3, h = th & 7;
    const int tid  = threadIdx.x;
    const int lane = tid & 63;
    const int w    = tid >> 6;
    const int l15  = lane & 15;
    const int hi4  = lane >> 4;
    const int wrow = w << 4;

    if (tid < 16) { glo[tid] = 256; ghi[tid] = -1; }
    __syncthreads();
    if (tid < 256) {
        const int g = gid[tid];
        sgid[tid] = g;
        atomicMin(&glo[g], tid);
        atomicMax(&ghi[g], tid);
    }

    const unsigned short* __restrict__ qb = qkvb + ((size_t)th << 14);
    const unsigned short* __restrict__ kb = qkvb + 33554432ull + ((size_t)th << 14);
    const unsigned short* __restrict__ vb = qkvb + 67108864ull + ((size_t)th << 14);

    // stage K (swizzled rows) and V (linear into Ps)
    {
        const int kr = tid >> 2, kq = tid & 3;
        const short8 k0 = *(const short8*)(kb + kr * 64 + kq * 16);
        const short8 k1 = *(const short8*)(kb + kr * 64 + kq * 16 + 8);
        *(short8*)&Ksh[swz64(kr, kq * 32)]      = k0;
        *(short8*)&Ksh[swz64(kr, kq * 32 + 16)] = k1;
        const short8 v0 = *(const short8*)(vb + kr * 64 + kq * 16);
        const short8 v1 = *(const short8*)(vb + kr * 64 + kq * 16 + 8);
        *(short8*)&Ps[kr * 64 + kq * 16]     = v0;
        *(short8*)&Ps[kr * 64 + kq * 16 + 8] = v1;
    }
    // Q fragments straight from global
    short8 qf[2];
    #pragma unroll
    for (int ks = 0; ks < 2; ++ks)
        qf[ks] = *(const short8*)(qb + (wrow + l15) * 64 + ks * 32 + hi4 * 8);
    __syncthreads();

    // transpose V: Ps[i][d] -> Vt[d][i] (swizzled)
    {
        const int d = tid & 63, jc = tid >> 6;
        short8 a, b;
        #pragma unroll
        for (int jj = 0; jj < 8; ++jj) a[jj] = Ps[(jc * 16 + jj) * 64 + d];
        #pragma unroll
        for (int jj = 0; jj < 8; ++jj) b[jj] = Ps[(jc * 16 + 8 + jj) * 64 + d];
        *(short8*)&Vt[swz256(d, jc * 32)]      = a;
        *(short8*)&Vt[swz256(d, jc * 32 + 16)] = b;
    }
    __syncthreads();

    // ---- group-restricted flash attention ----
    int rg[4];
    #pragma unroll
    for (int r = 0; r < 4; ++r) rg[r] = sgid[wrow + hi4 * 4 + r];
    const int klo = glo[sgid[wrow]];
    const int khi = ghi[sgid[wrow + 15]];

    f32x4 o[4];
    float mrun[4], lrun[4];
    #pragma unroll
    for (int n = 0; n < 4; ++n) o[n] = (f32x4){0.f, 0.f, 0.f, 0.f};
    #pragma unroll
    for (int r = 0; r < 4; ++r) { mrun[r] = -3.0e38f; lrun[r] = 0.f; }

    for (int kc = klo & ~63; kc <= khi; kc += 64) {
        f32x4 sfr[4];
        __builtin_amdgcn_s_setprio(1);
        #pragma unroll
        for (int n = 0; n < 4; ++n) {
            const int krow = kc + n * 16 + l15;
            const short8 kf0 = *(const short8*)&Ksh[swz64(krow, hi4 * 16)];
            const short8 kf1 = *(const short8*)&Ksh[swz64(krow, 64 + hi4 * 16)];
            f32x4 z = (f32x4){0.f, 0.f, 0.f, 0.f};
            z = MFMA16(qf[0], kf0, z);
            z = MFMA16(qf[1], kf1, z);
            sfr[n] = z;
        }
        __builtin_amdgcn_s_setprio(0);
        int cg[4];
        #pragma unroll
        for (int n = 0; n < 4; ++n) cg[n] = sgid[kc + n * 16 + l15];

        #pragma unroll
        for (int r = 0; r < 4; ++r) {
            const int gr = rg[r];
            float sv[4];
            float smax = -3.0e38f;
            #pragma unroll
            for (int n = 0; n < 4; ++n) {
                float x = sfr[n][r] * 0.125f;       // 1/sqrt(64)
                x = (cg[n] == gr) ? x : -3.0e38f;
                sv[n] = x;
                smax = fmaxf(smax, x);
            }
            smax = fmaxf(smax, __shfl_xor(smax, 1));
            smax = fmaxf(smax, __shfl_xor(smax, 2));
            smax = fmaxf(smax, __shfl_xor(smax, 4));
            smax = fmaxf(smax, __shfl_xor(smax, 8));
            const float newm = fmaxf(mrun[r], smax);
            const float corr = __expf(mrun[r] - newm);
            float ps = 0.f;
            unsigned short pb[4];
            #pragma unroll
            for (int n = 0; n < 4; ++n) {
                const float p = (sv[n] > -1.0e38f) ? __expf(sv[n] - newm) : 0.f;
                ps += p;
                pb[n] = f2bf(p);
            }
            ps += __shfl_xor(ps, 1); ps += __shfl_xor(ps, 2);
            ps += __shfl_xor(ps, 4); ps += __shfl_xor(ps, 8);
            lrun[r] = lrun[r] * corr + ps;
            mrun[r] = newm;
            #pragma unroll
            for (int n = 0; n < 4; ++n) o[n][r] *= corr;
            const int prow = wrow + hi4 * 4 + r;
            #pragma unroll
            for (int n = 0; n < 4; ++n)
                Ps[swz64(prow, (n * 16 + l15) * 2)] = pb[n];
        }

        const short8 pa0 = *(const short8*)&Ps[swz64(wrow + l15, hi4 * 16)];
        const short8 pa1 = *(const short8*)&Ps[swz64(wrow + l15, 64 + hi4 * 16)];
        __builtin_amdgcn_s_setprio(1);
        #pragma unroll
        for (int n = 0; n < 4; ++n) {
            const short8 vb0 = *(const short8*)&Vt[swz256(n * 16 + l15, (kc + hi4 * 8) * 2)];
            const short8 vb1 = *(const short8*)&Vt[swz256(n * 16 + l15, (kc + 32 + hi4 * 8) * 2)];
            o[n] = MFMA16(pa0, vb0, o[n]);
            o[n] = MFMA16(pa1, vb1, o[n]);
        }
        __builtin_amdgcn_s_setprio(0);
    }

    float* __restrict__ op = out + (size_t)t * (256 * 512) + h * 64;
    #pragma unroll
    for (int r = 0; r < 4; ++r) {
        const int row = wrow + hi4 * 4 + r;
        const float inv = 1.0f / lrun[r];
        #pragma unroll
        for (int n = 0; n < 4; ++n)
            op[(size_t)row * 512 + n * 16 + l15] = o[n][r] * inv;
    }
}

// ---------------------------------------------------------------------------
// FALLBACK (ws too small): round-4 fused QKV+attention kernel, unchanged.
// ---------------------------------------------------------------------------
__global__ __launch_bounds__(1024, 4) void qkv_attn_mfma(
    const float* __restrict__ hs,
    const int*   __restrict__ gid,
    const float* __restrict__ Wq, const float* __restrict__ Wk,
    const float* __restrict__ Wv,
    const unsigned short* __restrict__ wt,
    float*       __restrict__ out)
{
    __shared__ unsigned short Xs[256 * 64];
    __shared__ unsigned short Wsh[192 * 64];
    __shared__ unsigned short Ksh[256 * 64];
    __shared__ unsigned short Vt[64 * 256];
    __shared__ unsigned short XP[256 * 64];
    __shared__ int sgid[256];
    __shared__ int glo[16], ghi[16];

    const int bid = blockIdx.x;
    const int h   = (bid & 63) >> 3;
    const int t   = ((bid >> 6) << 3) + (bid & 7);

    const int tid  = threadIdx.x;
    const int lane = tid & 63;
    const int w    = tid >> 6;
    const int l15  = lane & 15;
    const int hi4  = lane >> 4;
    const int mg   = w & 3;
    const int ng   = w >> 2;

    if (tid < 16) { glo[tid] = 256; ghi[tid] = -1; }
    __syncthreads();
    if (tid < 256) {
        const int g = gid[tid];
        sgid[tid] = g;
        atomicMin(&glo[g], tid);
        atomicMax(&ghi[g], tid);
    }

    const float* __restrict__ Xbase = hs + (size_t)t * (256 * 512);

    const int xr = tid >> 2, xq = tid & 3;
    const bool doW = tid < 768;
    const int wc = tid >> 2;
    const int wq = tid & 3;
    const int wmat = wc >> 6, wcol = wc & 63;
    const unsigned short* __restrict__ wsrc =
        wt ? wt + ((size_t)wmat * 512 + h * 64 + wcol) * 512 : nullptr;
    const float* __restrict__ wfsrc =
        (wmat == 0) ? Wq : (wmat == 1) ? Wk : Wv;

    f32x4 acc[4][3];
    #pragma unroll
    for (int mt = 0; mt < 4; ++mt)
        #pragma unroll
        for (int nt = 0; nt < 3; ++nt)
            acc[mt][nt] = (f32x4){0.f, 0.f, 0.f, 0.f};

    float4 xf[4];
    short8 w8[2];
    {
        const float* s = Xbase + (size_t)xr * 512 + xq * 16;
        xf[0] = *(const float4*)(s + 0);  xf[1] = *(const float4*)(s + 4);
        xf[2] = *(const float4*)(s + 8);  xf[3] = *(const float4*)(s + 12);
        if (doW) {
            if (wt) {
                w8[0] = *(const short8*)(wsrc + wq * 16);
                w8[1] = *(const short8*)(wsrc + wq * 16 + 8);
            } else {
                #pragma unroll
                for (int b = 0; b < 2; ++b)
                    #pragma unroll
                    for (int j = 0; j < 8; ++j)
                        w8[b][j] = (short)f2bf(
                            wfsrc[(size_t)(wq * 16 + b * 8 + j) * 512 + h * 64 + wcol]);
            }
        }
    }

    for (int kb = 0; kb < 512; kb += 64) {
        *(short8*)&Xs[swz64(xr, xq * 32 + 0)]  = pack8(xf[0], xf[1]);
        *(short8*)&Xs[swz64(xr, xq * 32 + 16)] = pack8(xf[2], xf[3]);
        if (doW) {
            *(short8*)&Wsh[swz64(wc, wq * 32 + 0)]  = w8[0];
            *(short8*)&Wsh[swz64(wc, wq * 32 + 16)] = w8[1];
        }
        __syncthreads();
        if (kb < 448) {
            const int kn = kb + 64;
            const float* s = Xbase + (size_t)xr * 512 + kn + xq * 16;
            xf[0] = *(const float4*)(s + 0);  xf[1] = *(const float4*)(s + 4);
            xf[2] = *(const float4*)(s + 8);  xf[3] = *(const float4*)(s + 12);
            if (doW) {
                if (wt) {
                    w8[0] = *(const short8*)(wsrc + kn + wq * 16);
                    w8[1] = *(const short8*)(wsrc + kn + wq * 16 + 8);
                } else {
                    #pragma unroll
                    for (int b = 0; b < 2; ++b)
                        #pragma unroll
                        for (int j = 0; j < 8; ++j)
                            w8[b][j] = (short)f2bf(
                                wfsrc[(size_t)(kn + wq * 16 + b * 8 + j) * 512 + h * 64 + wcol]);
                }
            }
        }
        #pragma unroll
        for (int ks = 0; ks < 2; ++ks) {
            short8 af[4];
            #pragma unroll
            for (int mt = 0; mt < 4; ++mt)
                af[mt] = *(const short8*)&Xs[swz64(mg * 64 + mt * 16 + l15,
                                                   ks * 64 + hi4 * 16)];
            __builtin_amdgcn_s_setprio(1);
            #pragma unroll
            for (int nt = 0; nt < 3; ++nt) {
                const short8 bf = *(const short8*)&Wsh[swz64(ng * 48 + nt * 16 + l15,
                                                             ks * 64 + hi4 * 16)];
                #pragma unroll
                for (int mt = 0; mt < 4; ++mt)
                    acc[mt][nt] = MFMA16(af[mt], bf, acc[mt][nt]);
            }
            __builtin_amdgcn_s_setprio(0);
        }
        __syncthreads();
    }

    #pragma unroll
    for (int nt = 0; nt < 3; ++nt) {
        const int c0 = (ng * 3 + nt) * 16;
        const int m  = c0 >> 6;
        const int d0 = c0 & 63;
        #pragma unroll
        for (int mt = 0; mt < 4; ++mt) {
            const int rowb = mg * 64 + mt * 16 + hi4 * 4;
            if (m == 0) {
                #pragma unroll
                for (int r = 0; r < 4; ++r)
                    XP[swz64(rowb + r, (d0 + l15) * 2)] = f2bf(acc[mt][nt][r]);
            } else if (m == 1) {
                #pragma unroll
                for (int r = 0; r < 4; ++r)
                    Ksh[swz64(rowb + r, (d0 + l15) * 2)] = f2bf(acc[mt][nt][r]);
            } else {
                short4v vv;
                #pragma unroll
                for (int r = 0; r < 4; ++r) vv[r] = (short)f2bf(acc[mt][nt][r]);
                *(short4v*)&Vt[swz256(d0 + l15, rowb * 2)] = vv;
            }
        }
    }
    __syncthreads();

    const int wrow = w << 4;
    int rg[4];
    #pragma unroll
    for (int r = 0; r < 4; ++r) rg[r] = sgid[wrow + hi4 * 4 + r];
    const int klo = glo[sgid[wrow]];
    const int khi = ghi[sgid[wrow + 15]];

    short8 qf[2];
    #pragma unroll
    for (int ks = 0; ks < 2; ++ks)
        qf[ks] = *(const short8*)&XP[swz64(wrow + l15, ks * 64 + hi4 * 16)];

    f32x4 o[4];
    float mrun[4], lrun[4];
    #pragma unroll
    for (int n = 0; n < 4; ++n) o[n] = (f32x4){0.f, 0.f, 0.f, 0.f};
    #pragma unroll
    for (int r = 0; r < 4; ++r) { mrun[r] = -3.0e38f; lrun[r] = 0.f; }

    for (int kc = klo & ~63; kc <= khi; kc += 64) {
        f32x4 sfr[4];
        __builtin_amdgcn_s_setprio(1);
        #pragma unroll
        for (int n = 0; n < 4; ++n) {
            const int krow = kc + n * 16 + l15;
            const short8 kf0 = *(const short8*)&Ksh[swz64(krow, hi4 * 16)];
            const short8 kf1 = *(const short8*)&Ksh[swz64(krow, 64 + hi4 * 16)];
            f32x4 z = (f32x4){0.f, 0.f, 0.f, 0.f};
            z = MFMA16(qf[0], kf0, z);
            z = MFMA16(qf[1], kf1, z);
            sfr[n] = z;
        }
        __builtin_amdgcn_s_setprio(0);
        int cg[4];
        #pragma unroll
        for (int n = 0; n < 4; ++n) cg[n] = sgid[kc + n * 16 + l15];

        #pragma unroll
        for (int r = 0; r < 4; ++r) {
            const int gr = rg[r];
            float sv[4];
            float smax = -3.0e38f;
            #pragma unroll
            for (int n = 0; n < 4; ++n) {
                float x = sfr[n][r] * 0.125f;
                x = (cg[n] == gr) ? x : -3.0e38f;
                sv[n] = x;
                smax = fmaxf(smax, x);
            }
            smax = fmaxf(smax, __shfl_xor(smax, 1));
            smax = fmaxf(smax, __shfl_xor(smax, 2));
            smax = fmaxf(smax, __shfl_xor(smax, 4));
            smax = fmaxf(smax, __shfl_xor(smax, 8));
            const float newm = fmaxf(mrun[r], smax);
            const float corr = __expf(mrun[r] - newm);
            float ps = 0.f;
            unsigned short pb[4];
            #pragma unroll
            for (int n = 0; n < 4; ++n) {
                const float p = (sv[n] > -1.0e38f) ? __expf(sv[n] - newm) : 0.f;
                ps += p;
                pb[n] = f2bf(p);
            }
            ps += __shfl_xor(ps, 1); ps += __shfl_xor(ps, 2);
            ps += __shfl_xor(ps, 4); ps += __shfl_xor(ps, 8);
            lrun[r] = lrun[r] * corr + ps;
            mrun[r] = newm;
            #pragma unroll
            for (int n = 0; n < 4; ++n) o[n][r] *= corr;
            const int prow = wrow + hi4 * 4 + r;
            #pragma unroll
            for (int n = 0; n < 4; ++n)
                XP[swz64(prow, (n * 16 + l15) * 2)] = pb[n];
        }

        const short8 pa0 = *(const short8*)&XP[swz64(wrow + l15, hi4 * 16)];
        const short8 pa1 = *(const short8*)&XP[swz64(wrow + l15, 64 + hi4 * 16)];
        __builtin_amdgcn_s_setprio(1);
        #pragma unroll
        for (int n = 0; n < 4; ++n) {
            const short8 vb0 = *(const short8*)&Vt[swz256(n * 16 + l15, (kc + hi4 * 8) * 2)];
            const short8 vb1 = *(const short8*)&Vt[swz256(n * 16 + l15, (kc + 32 + hi4 * 8) * 2)];
            o[n] = MFMA16(pa0, vb0, o[n]);
            o[n] = MFMA16(pa1, vb1, o[n]);
        }
        __builtin_amdgcn_s_setprio(0);
    }

    float* __restrict__ op = out + (size_t)t * (256 * 512) + h * 64;
    #pragma unroll
    for (int r = 0; r < 4; ++r) {
        const int row = wrow + hi4 * 4 + r;
        const float inv = 1.0f / lrun[r];
        #pragma unroll
        for (int n = 0; n < 4; ++n)
            op[(size_t)row * 512 + n * 16 + l15] = o[n][r] * inv;
    }
}

// ---------------------------------------------------------------------------
// Kernel: out = attn @ Wo (f32, in-place over d_out). Block tile 128 x 512.
// ---------------------------------------------------------------------------
__global__ __launch_bounds__(1024, 4) void oproj_mfma(
    const float* __restrict__ Wo,
    const unsigned short* __restrict__ wot,
    float* __restrict__ out)
{
    __shared__ unsigned short As[128 * 40];
    __shared__ unsigned short Bts[512 * 40];

    const int tid  = threadIdx.x;
    const int lane = tid & 63;
    const int w    = tid >> 6;
    const int l15  = lane & 15;
    const int hi4  = lane >> 4;
    const int wr   = w >> 2;
    const int wc   = w & 3;
    const size_t r0 = (size_t)blockIdx.x * 128;

    f32x4 acc[2][8];
    #pragma unroll
    for (int m = 0; m < 2; ++m)
        #pragma unroll
        for (int n = 0; n < 8; ++n)
            acc[m][n] = (f32x4){0.f, 0.f, 0.f, 0.f};

    const bool isA = tid < 512;
    const int bn = tid & 511;
    const int ai = bn >> 2, aq = bn & 3;

    float4 af0, af1;
    short8 b8[4];

    if (isA) {
        const float* s = out + (r0 + ai) * 512 + aq * 8;
        af0 = *(const float4*)s; af1 = *(const float4*)(s + 4);
    } else {
        if (wot) {
            #pragma unroll
            for (int q = 0; q < 4; ++q)
                b8[q] = *(const short8*)(wot + (size_t)bn * 512 + q * 8);
        } else {
            #pragma unroll
            for (int q = 0; q < 4; ++q)
                #pragma unroll
                for (int j = 0; j < 8; ++j)
                    b8[q][j] = (short)f2bf(Wo[(size_t)(q * 8 + j) * 512 + bn]);
        }
    }

    for (int kb = 0; kb < 512; kb += 32) {
        if (isA) *(short8*)&As[ai * 40 + aq * 8] = pack8(af0, af1);
        else {
            #pragma unroll
            for (int q = 0; q < 4; ++q)
                *(short8*)&Bts[bn * 40 + q * 8] = b8[q];
        }
        __syncthreads();
        if (kb < 480) {
            const int kn = kb + 32;
            if (isA) {
                const float* s = out + (r0 + ai) * 512 + kn + aq * 8;
                af0 = *(const float4*)s; af1 = *(const float4*)(s + 4);
            } else {
                if (wot) {
                    #pragma unroll
                    for (int q = 0; q < 4; ++q)
                        b8[q] = *(const short8*)(wot + (size_t)bn * 512 + kn + q * 8);
                } else {
                    #pragma unroll
                    for (int q = 0; q < 4; ++q)
                        #pragma unroll
                        for (int j = 0; j < 8; ++j)
                            b8[q][j] = (short)f2bf(Wo[(size_t)(kn + q * 8 + j) * 512 + bn]);
                }
            }
        }
        short8 afr[2];
        #pragma unroll
        for (int m = 0; m < 2; ++m)
            afr[m] = *(const short8*)&As[(wr * 32 + m * 16 + l15) * 40 + hi4 * 8];
        __builtin_amdgcn_s_setprio(1);
        #pragma unroll
        for (int n = 0; n < 8; ++n) {
            const short8 bfr = *(const short8*)&Bts[(wc * 128 + n * 16 + l15) * 40 + hi4 * 8];
            #pragma unroll
            for (int m = 0; m < 2; ++m)
                acc[m][n] = MFMA16(afr[m], bfr, acc[m][n]);
        }
        __builtin_amdgcn_s_setprio(0);
        __syncthreads();
    }

    #pragma unroll
    for (int m = 0; m < 2; ++m)
        #pragma unroll
        for (int n = 0; n < 8; ++n)
            #pragma unroll
            for (int r = 0; r < 4; ++r)
                out[(r0 + wr * 32 + m * 16 + hi4 * 4 + r) * 512 + wc * 128 + n * 16 + l15] =
                    acc[m][n][r];
}

extern "C" void kernel_launch(void* const* d_in, const int* in_sizes, int n_in,
                              void* d_out, int out_size, void* d_ws, size_t ws_size,
                              hipStream_t stream) {
    const float* hs  = (const float*)d_in[0];
    const int*   gid = (const int*)  d_in[1];
    const float* Wq  = (const float*)d_in[2];
    const float* Wk  = (const float*)d_in[3];
    const float* Wv  = (const float*)d_in[4];
    const float* Wo  = (const float*)d_in[5];
    float* outp = (float*)d_out;

    const size_t WT_SHORTS  = 1048576;       // 4*512*512
    const size_t QKV_SHORTS = 100663296;     // 3*2048*256*64
    unsigned short* wt   = nullptr;
    unsigned short* wot  = nullptr;
    unsigned short* qkvb = nullptr;
    if (ws_size >= WT_SHORTS * 2) {
        wt  = (unsigned short*)d_ws;
        wot = wt + (size_t)3 * 262144;
        wprep<<<256, 256, 0, stream>>>(Wq, Wk, Wv, Wo, wt);
        if (ws_size >= (WT_SHORTS + QKV_SHORTS) * 2)
            qkvb = wt + WT_SHORTS;
    }

    if (qkvb) {
        qkv_gemm<<<1536, 1024, 0, stream>>>(hs, wt, qkvb);
        attn_split<<<2048, 1024, 0, stream>>>(qkvb, gid, outp);
    } else {
        qkv_attn_mfma<<<2048, 1024, 0, stream>>>(hs, gid, Wq, Wk, Wv, wt, outp);
    }
    oproj_mfma<<<512, 1024, 0, stream>>>(Wo, wot, outp);
}

// Round 6
// 351.776 us; speedup vs baseline: 1.0538x; 1.0538x over previous
//
#include <hip/hip_runtime.h>
#include <hip/hip_bf16.h>

typedef __attribute__((ext_vector_type(8))) short short8;
typedef __attribute__((ext_vector_type(4))) short short4v;
typedef __attribute__((ext_vector_type(4))) float f32x4;

#define MFMA16(a, b, c) __builtin_amdgcn_mfma_f32_16x16x32_bf16(a, b, c, 0, 0, 0)

__device__ __forceinline__ unsigned short f2bf(float f) {
    union { __hip_bfloat16 h; unsigned short u; } v;
    v.h = __float2bfloat16(f);
    return v.u;
}

__device__ __forceinline__ short8 pack8(float4 a, float4 b) {
    short8 p;
    p[0] = (short)f2bf(a.x); p[1] = (short)f2bf(a.y);
    p[2] = (short)f2bf(a.z); p[3] = (short)f2bf(a.w);
    p[4] = (short)f2bf(b.x); p[5] = (short)f2bf(b.y);
    p[6] = (short)f2bf(b.z); p[7] = (short)f2bf(b.w);
    return p;
}

// XOR-swizzled LDS indexing (T2): linear rows, byte ^= (row&7)<<4.
__device__ __forceinline__ int swz64(int row, int bytecol) {   // 64-short rows
    return row * 64 + ((bytecol ^ ((row & 7) << 4)) >> 1);
}
__device__ __forceinline__ int swz256(int row, int bytecol) {  // 256-short rows
    return row * 256 + ((bytecol ^ ((row & 7) << 4)) >> 1);
}

// ---------------------------------------------------------------------------
// Weight prep: wt[m][n][k] = W_m[k][n] as bf16, m in {Wq,Wk,Wv,Wo}.
// ---------------------------------------------------------------------------
__global__ __launch_bounds__(256) void wprep(
    const float* __restrict__ Wq, const float* __restrict__ Wk,
    const float* __restrict__ Wv, const float* __restrict__ Wo,
    unsigned short* __restrict__ wt)
{
    __shared__ float tile[64][65];
    const int bid = blockIdx.x;
    const int m = bid >> 6, tb = bid & 63;
    const int kr = (tb >> 3) << 6, nc = (tb & 7) << 6;
    const float* W = (m == 0) ? Wq : (m == 1) ? Wk : (m == 2) ? Wv : Wo;
    const int tid = threadIdx.x;
    for (int i = tid; i < 4096; i += 256)
        tile[i >> 6][i & 63] = W[(size_t)(kr + (i >> 6)) * 512 + nc + (i & 63)];
    __syncthreads();
    unsigned short* dst = wt + (size_t)m * 262144;
    for (int i = tid; i < 4096; i += 256)
        dst[(size_t)(nc + (i >> 6)) * 512 + kr + (i & 63)] = f2bf(tile[i & 63][i >> 6]);
}

// ---------------------------------------------------------------------------
// QKV GEMM v2: qkvb[mat][row][col] (bf16, [3][65536][512]) = X @ W_mat.
// Block tile 128 rows x 512 cols (mat nb per block), BK=64, 1024 thr =
// 16 waves (2 wr x 8 wc), wave tile 64x64. Swizzled LDS (swz64) kills the
// 8-way fragment-read conflicts; 16 ds_read_b128 per 32 MFMA per K-step.
// bid remap: each XCD gets 64 consecutive mb x 3 mats (A-tile L2 reuse).
// ---------------------------------------------------------------------------
__global__ __launch_bounds__(1024, 4) void qkv_gemm2(
    const float* __restrict__ hs,            // [65536][512] f32
    const unsigned short* __restrict__ wt,   // [4][512][512] bf16 W^T
    unsigned short* __restrict__ qkvb)       // [3][65536][512] bf16
{
    __shared__ unsigned short As[128 * 64];   // 16 KB, swizzled
    __shared__ unsigned short Bts[512 * 64];  // 64 KB, swizzled

    const int orig = blockIdx.x;             // 1536
    const int wg = (orig & 7) * 192 + (orig >> 3);
    const int mb = wg / 3;
    const int nb = wg - mb * 3;

    const int tid  = threadIdx.x;
    const int lane = tid & 63;
    const int w    = tid >> 6;
    const int l15  = lane & 15;
    const int hi4  = lane >> 4;
    const int wr   = w >> 3;        // 0..1  (64-row strip)
    const int wc   = w & 7;         // 0..7  (64-col strip)

    f32x4 acc[4][4];
    #pragma unroll
    for (int mt = 0; mt < 4; ++mt)
        #pragma unroll
        for (int nt = 0; nt < 4; ++nt)
            acc[mt][nt] = (f32x4){0.f, 0.f, 0.f, 0.f};

    // staging: A: 128 rows x 64 k f32 (8 floats/thread);
    //          B: 512 cols x 64 k bf16 (32 shorts/thread)
    const int ar = tid >> 3, aq = tid & 7;
    const int bc = tid >> 1, bh = tid & 1;
    const float* __restrict__ asrc = hs + ((size_t)mb * 128 + ar) * 512 + aq * 8;
    const unsigned short* __restrict__ bsrc =
        wt + ((size_t)nb * 512 + bc) * 512 + bh * 32;

    float4 a0, a1;
    short8 b8[4];
    a0 = *(const float4*)asrc;
    a1 = *(const float4*)(asrc + 4);
    #pragma unroll
    for (int q = 0; q < 4; ++q) b8[q] = *(const short8*)(bsrc + q * 8);

    for (int kb = 0; kb < 512; kb += 64) {
        *(short8*)&As[swz64(ar, aq * 16)] = pack8(a0, a1);
        #pragma unroll
        for (int q = 0; q < 4; ++q)
            *(short8*)&Bts[swz64(bc, bh * 64 + q * 16)] = b8[q];
        __syncthreads();
        if (kb < 448) {
            const int kn = kb + 64;
            a0 = *(const float4*)(asrc + kn);
            a1 = *(const float4*)(asrc + kn + 4);
            #pragma unroll
            for (int q = 0; q < 4; ++q)
                b8[q] = *(const short8*)(bsrc + kn + q * 8);
        }
        #pragma unroll
        for (int ks = 0; ks < 2; ++ks) {
            short8 af[4];
            #pragma unroll
            for (int mt = 0; mt < 4; ++mt)
                af[mt] = *(const short8*)&As[swz64(wr * 64 + mt * 16 + l15,
                                                   ks * 64 + hi4 * 16)];
            __builtin_amdgcn_s_setprio(1);
            #pragma unroll
            for (int nt = 0; nt < 4; ++nt) {
                const short8 bf = *(const short8*)&Bts[swz64(wc * 64 + nt * 16 + l15,
                                                             ks * 64 + hi4 * 16)];
                #pragma unroll
                for (int mt = 0; mt < 4; ++mt)
                    acc[mt][nt] = MFMA16(af[mt], bf, acc[mt][nt]);
            }
            __builtin_amdgcn_s_setprio(0);
        }
        __syncthreads();
    }

    // epilogue: bf16 scatter into [mat][row][col]
    unsigned short* __restrict__ dst = qkvb + (size_t)nb * 33554432ull;
    #pragma unroll
    for (int mt = 0; mt < 4; ++mt) {
        #pragma unroll
        for (int nt = 0; nt < 4; ++nt) {
            const int col = wc * 64 + nt * 16 + l15;
            #pragma unroll
            for (int r = 0; r < 4; ++r) {
                const int row = mb * 128 + wr * 64 + mt * 16 + hi4 * 4 + r;
                dst[(size_t)row * 512 + col] = f2bf(acc[mt][nt][r]);
            }
        }
    }
}

// ---------------------------------------------------------------------------
// Attention: one block per (t,h). K (swizzled) + V (transpose->Vt swizzled)
// staged from qkvb [mat][65536][512]; Q fragments straight to registers.
// 1024 thr = 16 waves, wave = 16 Q-rows. Group-restricted flash loop.
// ---------------------------------------------------------------------------
__global__ __launch_bounds__(1024, 4) void attn_split(
    const unsigned short* __restrict__ qkvb,
    const int* __restrict__ gid,
    unsigned short* __restrict__ abuf,       // bf16 attn-out or null
    float* __restrict__ out)                 // [256][256][512] f32
{
    __shared__ unsigned short Ksh[256 * 64];
    __shared__ unsigned short Vt[64 * 256];
    __shared__ unsigned short Ps[256 * 64];  // V-transit, then P tiles
    __shared__ int sgid[256];
    __shared__ int glo[16], ghi[16];

    const int th = blockIdx.x;               // t*8+h
    const int t = th >> 3, h = th & 7;
    const int tid  = threadIdx.x;
    const int lane = tid & 63;
    const int w    = tid >> 6;
    const int l15  = lane & 15;
    const int hi4  = lane >> 4;
    const int wrow = w << 4;

    if (tid < 16) { glo[tid] = 256; ghi[tid] = -1; }
    __syncthreads();
    if (tid < 256) {
        const int g = gid[tid];
        sgid[tid] = g;
        atomicMin(&glo[g], tid);
        atomicMax(&ghi[g], tid);
    }

    const size_t rowbase = (size_t)t * 256 * 512 + h * 64;
    const unsigned short* __restrict__ qb = qkvb + rowbase;
    const unsigned short* __restrict__ kbp = qkvb + 33554432ull + rowbase;
    const unsigned short* __restrict__ vbp = qkvb + 67108864ull + rowbase;

    // stage K (swizzled rows) and V (linear into Ps)
    {
        const int kr = tid >> 2, kq = tid & 3;
        const short8 k0 = *(const short8*)(kbp + (size_t)kr * 512 + kq * 16);
        const short8 k1 = *(const short8*)(kbp + (size_t)kr * 512 + kq * 16 + 8);
        *(short8*)&Ksh[swz64(kr, kq * 32)]      = k0;
        *(short8*)&Ksh[swz64(kr, kq * 32 + 16)] = k1;
        const short8 v0 = *(const short8*)(vbp + (size_t)kr * 512 + kq * 16);
        const short8 v1 = *(const short8*)(vbp + (size_t)kr * 512 + kq * 16 + 8);
        *(short8*)&Ps[kr * 64 + kq * 16]     = v0;
        *(short8*)&Ps[kr * 64 + kq * 16 + 8] = v1;
    }
    // Q fragments straight from global
    short8 qf[2];
    #pragma unroll
    for (int ks = 0; ks < 2; ++ks)
        qf[ks] = *(const short8*)(qb + (size_t)(wrow + l15) * 512 + ks * 32 + hi4 * 8);
    __syncthreads();

    // transpose V: Ps[i][d] -> Vt[d][i] (swizzled)
    {
        const int d = tid & 63, jc = tid >> 6;
        short8 a, b;
        #pragma unroll
        for (int jj = 0; jj < 8; ++jj) a[jj] = Ps[(jc * 16 + jj) * 64 + d];
        #pragma unroll
        for (int jj = 0; jj < 8; ++jj) b[jj] = Ps[(jc * 16 + 8 + jj) * 64 + d];
        *(short8*)&Vt[swz256(d, jc * 32)]      = a;
        *(short8*)&Vt[swz256(d, jc * 32 + 16)] = b;
    }
    __syncthreads();

    // ---- group-restricted flash attention ----
    int rg[4];
    #pragma unroll
    for (int r = 0; r < 4; ++r) rg[r] = sgid[wrow + hi4 * 4 + r];
    const int klo = glo[sgid[wrow]];
    const int khi = ghi[sgid[wrow + 15]];

    f32x4 o[4];
    float mrun[4], lrun[4];
    #pragma unroll
    for (int n = 0; n < 4; ++n) o[n] = (f32x4){0.f, 0.f, 0.f, 0.f};
    #pragma unroll
    for (int r = 0; r < 4; ++r) { mrun[r] = -3.0e38f; lrun[r] = 0.f; }

    for (int kc = klo & ~63; kc <= khi; kc += 64) {
        f32x4 sfr[4];
        __builtin_amdgcn_s_setprio(1);
        #pragma unroll
        for (int n = 0; n < 4; ++n) {
            const int krow = kc + n * 16 + l15;
            const short8 kf0 = *(const short8*)&Ksh[swz64(krow, hi4 * 16)];
            const short8 kf1 = *(const short8*)&Ksh[swz64(krow, 64 + hi4 * 16)];
            f32x4 z = (f32x4){0.f, 0.f, 0.f, 0.f};
            z = MFMA16(qf[0], kf0, z);
            z = MFMA16(qf[1], kf1, z);
            sfr[n] = z;
        }
        __builtin_amdgcn_s_setprio(0);
        int cg[4];
        #pragma unroll
        for (int n = 0; n < 4; ++n) cg[n] = sgid[kc + n * 16 + l15];

        #pragma unroll
        for (int r = 0; r < 4; ++r) {
            const int gr = rg[r];
            float sv[4];
            float smax = -3.0e38f;
            #pragma unroll
            for (int n = 0; n < 4; ++n) {
                float x = sfr[n][r] * 0.125f;       // 1/sqrt(64)
                x = (cg[n] == gr) ? x : -3.0e38f;
                sv[n] = x;
                smax = fmaxf(smax, x);
            }
            smax = fmaxf(smax, __shfl_xor(smax, 1));
            smax = fmaxf(smax, __shfl_xor(smax, 2));
            smax = fmaxf(smax, __shfl_xor(smax, 4));
            smax = fmaxf(smax, __shfl_xor(smax, 8));
            const float newm = fmaxf(mrun[r], smax);
            const float corr = __expf(mrun[r] - newm);
            float ps = 0.f;
            unsigned short pb[4];
            #pragma unroll
            for (int n = 0; n < 4; ++n) {
                const float p = (sv[n] > -1.0e38f) ? __expf(sv[n] - newm) : 0.f;
                ps += p;
                pb[n] = f2bf(p);
            }
            ps += __shfl_xor(ps, 1); ps += __shfl_xor(ps, 2);
            ps += __shfl_xor(ps, 4); ps += __shfl_xor(ps, 8);
            lrun[r] = lrun[r] * corr + ps;
            mrun[r] = newm;
            #pragma unroll
            for (int n = 0; n < 4; ++n) o[n][r] *= corr;
            const int prow = wrow + hi4 * 4 + r;
            #pragma unroll
            for (int n = 0; n < 4; ++n)
                Ps[swz64(prow, (n * 16 + l15) * 2)] = pb[n];
        }

        const short8 pa0 = *(const short8*)&Ps[swz64(wrow + l15, hi4 * 16)];
        const short8 pa1 = *(const short8*)&Ps[swz64(wrow + l15, 64 + hi4 * 16)];
        __builtin_amdgcn_s_setprio(1);
        #pragma unroll
        for (int n = 0; n < 4; ++n) {
            const short8 vb0 = *(const short8*)&Vt[swz256(n * 16 + l15, (kc + hi4 * 8) * 2)];
            const short8 vb1 = *(const short8*)&Vt[swz256(n * 16 + l15, (kc + 32 + hi4 * 8) * 2)];
            o[n] = MFMA16(pa0, vb0, o[n]);
            o[n] = MFMA16(pa1, vb1, o[n]);
        }
        __builtin_amdgcn_s_setprio(0);
    }

    if (abuf) {
        unsigned short* __restrict__ op = abuf + rowbase;
        #pragma unroll
        for (int r = 0; r < 4; ++r) {
            const int row = wrow + hi4 * 4 + r;
            const float inv = 1.0f / lrun[r];
            #pragma unroll
            for (int n = 0; n < 4; ++n)
                op[(size_t)row * 512 + n * 16 + l15] = f2bf(o[n][r] * inv);
        }
    } else {
        float* __restrict__ op = out + rowbase;
        #pragma unroll
        for (int r = 0; r < 4; ++r) {
            const int row = wrow + hi4 * 4 + r;
            const float inv = 1.0f / lrun[r];
            #pragma unroll
            for (int n = 0; n < 4; ++n)
                op[(size_t)row * 512 + n * 16 + l15] = o[n][r] * inv;
        }
    }
}

// ---------------------------------------------------------------------------
// FALLBACK (ws too small): round-4 fused QKV+attention kernel, unchanged.
// ---------------------------------------------------------------------------
__global__ __launch_bounds__(1024, 4) void qkv_attn_mfma(
    const float* __restrict__ hs,
    const int*   __restrict__ gid,
    const float* __restrict__ Wq, const float* __restrict__ Wk,
    const float* __restrict__ Wv,
    const unsigned short* __restrict__ wt,
    float*       __restrict__ out)
{
    __shared__ unsigned short Xs[256 * 64];
    __shared__ unsigned short Wsh[192 * 64];
    __shared__ unsigned short Ksh[256 * 64];
    __shared__ unsigned short Vt[64 * 256];
    __shared__ unsigned short XP[256 * 64];
    __shared__ int sgid[256];
    __shared__ int glo[16], ghi[16];

    const int bid = blockIdx.x;
    const int h   = (bid & 63) >> 3;
    const int t   = ((bid >> 6) << 3) + (bid & 7);

    const int tid  = threadIdx.x;
    const int lane = tid & 63;
    const int w    = tid >> 6;
    const int l15  = lane & 15;
    const int hi4  = lane >> 4;
    const int mg   = w & 3;
    const int ng   = w >> 2;

    if (tid < 16) { glo[tid] = 256; ghi[tid] = -1; }
    __syncthreads();
    if (tid < 256) {
        const int g = gid[tid];
        sgid[tid] = g;
        atomicMin(&glo[g], tid);
        atomicMax(&ghi[g], tid);
    }

    const float* __restrict__ Xbase = hs + (size_t)t * (256 * 512);

    const int xr = tid >> 2, xq = tid & 3;
    const bool doW = tid < 768;
    const int wc = tid >> 2;
    const int wq = tid & 3;
    const int wmat = wc >> 6, wcol = wc & 63;
    const unsigned short* __restrict__ wsrc =
        wt ? wt + ((size_t)wmat * 512 + h * 64 + wcol) * 512 : nullptr;
    const float* __restrict__ wfsrc =
        (wmat == 0) ? Wq : (wmat == 1) ? Wk : Wv;

    f32x4 acc[4][3];
    #pragma unroll
    for (int mt = 0; mt < 4; ++mt)
        #pragma unroll
        for (int nt = 0; nt < 3; ++nt)
            acc[mt][nt] = (f32x4){0.f, 0.f, 0.f, 0.f};

    float4 xf[4];
    short8 w8[2];
    {
        const float* s = Xbase + (size_t)xr * 512 + xq * 16;
        xf[0] = *(const float4*)(s + 0);  xf[1] = *(const float4*)(s + 4);
        xf[2] = *(const float4*)(s + 8);  xf[3] = *(const float4*)(s + 12);
        if (doW) {
            if (wt) {
                w8[0] = *(const short8*)(wsrc + wq * 16);
                w8[1] = *(const short8*)(wsrc + wq * 16 + 8);
            } else {
                #pragma unroll
                for (int b = 0; b < 2; ++b)
                    #pragma unroll
                    for (int j = 0; j < 8; ++j)
                        w8[b][j] = (short)f2bf(
                            wfsrc[(size_t)(wq * 16 + b * 8 + j) * 512 + h * 64 + wcol]);
            }
        }
    }

    for (int kb = 0; kb < 512; kb += 64) {
        *(short8*)&Xs[swz64(xr, xq * 32 + 0)]  = pack8(xf[0], xf[1]);
        *(short8*)&Xs[swz64(xr, xq * 32 + 16)] = pack8(xf[2], xf[3]);
        if (doW) {
            *(short8*)&Wsh[swz64(wc, wq * 32 + 0)]  = w8[0];
            *(short8*)&Wsh[swz64(wc, wq * 32 + 16)] = w8[1];
        }
        __syncthreads();
        if (kb < 448) {
            const int kn = kb + 64;
            const float* s = Xbase + (size_t)xr * 512 + kn + xq * 16;
            xf[0] = *(const float4*)(s + 0);  xf[1] = *(const float4*)(s + 4);
            xf[2] = *(const float4*)(s + 8);  xf[3] = *(const float4*)(s + 12);
            if (doW) {
                if (wt) {
                    w8[0] = *(const short8*)(wsrc + kn + wq * 16);
                    w8[1] = *(const short8*)(wsrc + kn + wq * 16 + 8);
                } else {
                    #pragma unroll
                    for (int b = 0; b < 2; ++b)
                        #pragma unroll
                        for (int j = 0; j < 8; ++j)
                            w8[b][j] = (short)f2bf(
                                wfsrc[(size_t)(kn + wq * 16 + b * 8 + j) * 512 + h * 64 + wcol]);
                }
            }
        }
        #pragma unroll
        for (int ks = 0; ks < 2; ++ks) {
            short8 af[4];
            #pragma unroll
            for (int mt = 0; mt < 4; ++mt)
                af[mt] = *(const short8*)&Xs[swz64(mg * 64 + mt * 16 + l15,
                                                   ks * 64 + hi4 * 16)];
            __builtin_amdgcn_s_setprio(1);
            #pragma unroll
            for (int nt = 0; nt < 3; ++nt) {
                const short8 bf = *(const short8*)&Wsh[swz64(ng * 48 + nt * 16 + l15,
                                                             ks * 64 + hi4 * 16)];
                #pragma unroll
                for (int mt = 0; mt < 4; ++mt)
                    acc[mt][nt] = MFMA16(af[mt], bf, acc[mt][nt]);
            }
            __builtin_amdgcn_s_setprio(0);
        }
        __syncthreads();
    }

    #pragma unroll
    for (int nt = 0; nt < 3; ++nt) {
        const int c0 = (ng * 3 + nt) * 16;
        const int m  = c0 >> 6;
        const int d0 = c0 & 63;
        #pragma unroll
        for (int mt = 0; mt < 4; ++mt) {
            const int rowb = mg * 64 + mt * 16 + hi4 * 4;
            if (m == 0) {
                #pragma unroll
                for (int r = 0; r < 4; ++r)
                    XP[swz64(rowb + r, (d0 + l15) * 2)] = f2bf(acc[mt][nt][r]);
            } else if (m == 1) {
                #pragma unroll
                for (int r = 0; r < 4; ++r)
                    Ksh[swz64(rowb + r, (d0 + l15) * 2)] = f2bf(acc[mt][nt][r]);
            } else {
                short4v vv;
                #pragma unroll
                for (int r = 0; r < 4; ++r) vv[r] = (short)f2bf(acc[mt][nt][r]);
                *(short4v*)&Vt[swz256(d0 + l15, rowb * 2)] = vv;
            }
        }
    }
    __syncthreads();

    const int wrow = w << 4;
    int rg[4];
    #pragma unroll
    for (int r = 0; r < 4; ++r) rg[r] = sgid[wrow + hi4 * 4 + r];
    const int klo = glo[sgid[wrow]];
    const int khi = ghi[sgid[wrow + 15]];

    short8 qf[2];
    #pragma unroll
    for (int ks = 0; ks < 2; ++ks)
        qf[ks] = *(const short8*)&XP[swz64(wrow + l15, ks * 64 + hi4 * 16)];

    f32x4 o[4];
    float mrun[4], lrun[4];
    #pragma unroll
    for (int n = 0; n < 4; ++n) o[n] = (f32x4){0.f, 0.f, 0.f, 0.f};
    #pragma unroll
    for (int r = 0; r < 4; ++r) { mrun[r] = -3.0e38f; lrun[r] = 0.f; }

    for (int kc = klo & ~63; kc <= khi; kc += 64) {
        f32x4 sfr[4];
        __builtin_amdgcn_s_setprio(1);
        #pragma unroll
        for (int n = 0; n < 4; ++n) {
            const int krow = kc + n * 16 + l15;
            const short8 kf0 = *(const short8*)&Ksh[swz64(krow, hi4 * 16)];
            const short8 kf1 = *(const short8*)&Ksh[swz64(krow, 64 + hi4 * 16)];
            f32x4 z = (f32x4){0.f, 0.f, 0.f, 0.f};
            z = MFMA16(qf[0], kf0, z);
            z = MFMA16(qf[1], kf1, z);
            sfr[n] = z;
        }
        __builtin_amdgcn_s_setprio(0);
        int cg[4];
        #pragma unroll
        for (int n = 0; n < 4; ++n) cg[n] = sgid[kc + n * 16 + l15];

        #pragma unroll
        for (int r = 0; r < 4; ++r) {
            const int gr = rg[r];
            float sv[4];
            float smax = -3.0e38f;
            #pragma unroll
            for (int n = 0; n < 4; ++n) {
                float x = sfr[n][r] * 0.125f;
                x = (cg[n] == gr) ? x : -3.0e38f;
                sv[n] = x;
                smax = fmaxf(smax, x);
            }
            smax = fmaxf(smax, __shfl_xor(smax, 1));
            smax = fmaxf(smax, __shfl_xor(smax, 2));
            smax = fmaxf(smax, __shfl_xor(smax, 4));
            smax = fmaxf(smax, __shfl_xor(smax, 8));
            const float newm = fmaxf(mrun[r], smax);
            const float corr = __expf(mrun[r] - newm);
            float ps = 0.f;
            unsigned short pb[4];
            #pragma unroll
            for (int n = 0; n < 4; ++n) {
                const float p = (sv[n] > -1.0e38f) ? __expf(sv[n] - newm) : 0.f;
                ps += p;
                pb[n] = f2bf(p);
            }
            ps += __shfl_xor(ps, 1); ps += __shfl_xor(ps, 2);
            ps += __shfl_xor(ps, 4); ps += __shfl_xor(ps, 8);
            lrun[r] = lrun[r] * corr + ps;
            mrun[r] = newm;
            #pragma unroll
            for (int n = 0; n < 4; ++n) o[n][r] *= corr;
            const int prow = wrow + hi4 * 4 + r;
            #pragma unroll
            for (int n = 0; n < 4; ++n)
                XP[swz64(prow, (n * 16 + l15) * 2)] = pb[n];
        }

        const short8 pa0 = *(const short8*)&XP[swz64(wrow + l15, hi4 * 16)];
        const short8 pa1 = *(const short8*)&XP[swz64(wrow + l15, 64 + hi4 * 16)];
        __builtin_amdgcn_s_setprio(1);
        #pragma unroll
        for (int n = 0; n < 4; ++n) {
            const short8 vb0 = *(const short8*)&Vt[swz256(n * 16 + l15, (kc + hi4 * 8) * 2)];
            const short8 vb1 = *(const short8*)&Vt[swz256(n * 16 + l15, (kc + 32 + hi4 * 8) * 2)];
            o[n] = MFMA16(pa0, vb0, o[n]);
            o[n] = MFMA16(pa1, vb1, o[n]);
        }
        __builtin_amdgcn_s_setprio(0);
    }

    float* __restrict__ op = out + (size_t)t * (256 * 512) + h * 64;
    #pragma unroll
    for (int r = 0; r < 4; ++r) {
        const int row = wrow + hi4 * 4 + r;
        const float inv = 1.0f / lrun[r];
        #pragma unroll
        for (int n = 0; n < 4; ++n)
            op[(size_t)row * 512 + n * 16 + l15] = o[n][r] * inv;
    }
}

// ---------------------------------------------------------------------------
// Kernel: out = attn @ Wo. A from bf16 abuf (preferred) or f32 out in-place.
// Block tile 128 x 512, BK=32, 16 waves (4x4), wave tile 32x128.
// ---------------------------------------------------------------------------
__global__ __launch_bounds__(1024, 4) void oproj_mfma(
    const float* __restrict__ Wo,
    const unsigned short* __restrict__ wot,
    const unsigned short* __restrict__ abuf,
    float* __restrict__ out)
{
    __shared__ unsigned short As[128 * 40];
    __shared__ unsigned short Bts[512 * 40];

    const int tid  = threadIdx.x;
    const int lane = tid & 63;
    const int w    = tid >> 6;
    const int l15  = lane & 15;
    const int hi4  = lane >> 4;
    const int wr   = w >> 2;
    const int wc   = w & 3;
    const size_t r0 = (size_t)blockIdx.x * 128;

    f32x4 acc[2][8];
    #pragma unroll
    for (int m = 0; m < 2; ++m)
        #pragma unroll
        for (int n = 0; n < 8; ++n)
            acc[m][n] = (f32x4){0.f, 0.f, 0.f, 0.f};

    const bool isA = tid < 512;
    const int bn = tid & 511;
    const int ai = bn >> 2, aq = bn & 3;

    float4 af0, af1;
    short8 a8;
    short8 b8[4];

    if (isA) {
        if (abuf) {
            a8 = *(const short8*)(abuf + (r0 + ai) * 512 + aq * 8);
        } else {
            const float* s = out + (r0 + ai) * 512 + aq * 8;
            af0 = *(const float4*)s; af1 = *(const float4*)(s + 4);
        }
    } else {
        if (wot) {
            #pragma unroll
            for (int q = 0; q < 4; ++q)
                b8[q] = *(const short8*)(wot + (size_t)bn * 512 + q * 8);
        } else {
            #pragma unroll
            for (int q = 0; q < 4; ++q)
                #pragma unroll
                for (int j = 0; j < 8; ++j)
                    b8[q][j] = (short)f2bf(Wo[(size_t)(q * 8 + j) * 512 + bn]);
        }
    }

    for (int kb = 0; kb < 512; kb += 32) {
        if (isA) *(short8*)&As[ai * 40 + aq * 8] = abuf ? a8 : pack8(af0, af1);
        else {
            #pragma unroll
            for (int q = 0; q < 4; ++q)
                *(short8*)&Bts[bn * 40 + q * 8] = b8[q];
        }
        __syncthreads();
        if (kb < 480) {
            const int kn = kb + 32;
            if (isA) {
                if (abuf) {
                    a8 = *(const short8*)(abuf + (r0 + ai) * 512 + kn + aq * 8);
                } else {
                    const float* s = out + (r0 + ai) * 512 + kn + aq * 8;
                    af0 = *(const float4*)s; af1 = *(const float4*)(s + 4);
                }
            } else {
                if (wot) {
                    #pragma unroll
                    for (int q = 0; q < 4; ++q)
                        b8[q] = *(const short8*)(wot + (size_t)bn * 512 + kn + q * 8);
                } else {
                    #pragma unroll
                    for (int q = 0; q < 4; ++q)
                        #pragma unroll
                        for (int j = 0; j < 8; ++j)
                            b8[q][j] = (short)f2bf(Wo[(size_t)(kn + q * 8 + j) * 512 + bn]);
                }
            }
        }
        short8 afr[2];
        #pragma unroll
        for (int m = 0; m < 2; ++m)
            afr[m] = *(const short8*)&As[(wr * 32 + m * 16 + l15) * 40 + hi4 * 8];
        __builtin_amdgcn_s_setprio(1);
        #pragma unroll
        for (int n = 0; n < 8; ++n) {
            const short8 bfr = *(const short8*)&Bts[(wc * 128 + n * 16 + l15) * 40 + hi4 * 8];
            #pragma unroll
            for (int m = 0; m < 2; ++m)
                acc[m][n] = MFMA16(afr[m], bfr, acc[m][n]);
        }
        __builtin_amdgcn_s_setprio(0);
        __syncthreads();
    }

    #pragma unroll
    for (int m = 0; m < 2; ++m)
        #pragma unroll
        for (int n = 0; n < 8; ++n)
            #pragma unroll
            for (int r = 0; r < 4; ++r)
                out[(r0 + wr * 32 + m * 16 + hi4 * 4 + r) * 512 + wc * 128 + n * 16 + l15] =
                    acc[m][n][r];
}

extern "C" void kernel_launch(void* const* d_in, const int* in_sizes, int n_in,
                              void* d_out, int out_size, void* d_ws, size_t ws_size,
                              hipStream_t stream) {
    const float* hs  = (const float*)d_in[0];
    const int*   gid = (const int*)  d_in[1];
    const float* Wq  = (const float*)d_in[2];
    const float* Wk  = (const float*)d_in[3];
    const float* Wv  = (const float*)d_in[4];
    const float* Wo  = (const float*)d_in[5];
    float* outp = (float*)d_out;

    const size_t WT_S  = 1048576;        //  2 MB (shorts)
    const size_t QKV_S = 100663296;      //  201 MB
    const size_t AB_S  = 33554432;       //  67 MB
    unsigned short* wt   = nullptr;
    unsigned short* wot  = nullptr;
    unsigned short* qkvb = nullptr;
    unsigned short* abuf = nullptr;
    if (ws_size >= WT_S * 2) {
        wt  = (unsigned short*)d_ws;
        wot = wt + (size_t)3 * 262144;
        wprep<<<256, 256, 0, stream>>>(Wq, Wk, Wv, Wo, wt);
        if (ws_size >= (WT_S + QKV_S) * 2)
            qkvb = wt + WT_S;
        if (ws_size >= (WT_S + QKV_S + AB_S) * 2)
            abuf = wt + WT_S + QKV_S;
    }

    if (qkvb) {
        qkv_gemm2<<<1536, 1024, 0, stream>>>(hs, wt, qkvb);
        attn_split<<<2048, 1024, 0, stream>>>(qkvb, gid, abuf, outp);
    } else {
        qkv_attn_mfma<<<2048, 1024, 0, stream>>>(hs, gid, Wq, Wk, Wv, wt, outp);
    }
    oproj_mfma<<<512, 1024, 0, stream>>>(Wo, wot, abuf, outp);
}

// Round 7
// 341.072 us; speedup vs baseline: 1.0869x; 1.0314x over previous
//
#include <hip/hip_runtime.h>
#include <hip/hip_bf16.h>

typedef __attribute__((ext_vector_type(8))) short short8;
typedef __attribute__((ext_vector_type(4))) short short4v;
typedef __attribute__((ext_vector_type(4))) float f32x4;

#define MFMA16(a, b, c) __builtin_amdgcn_mfma_f32_16x16x32_bf16(a, b, c, 0, 0, 0)

__device__ __forceinline__ unsigned short f2bf(float f) {
    union { __hip_bfloat16 h; unsigned short u; } v;
    v.h = __float2bfloat16(f);
    return v.u;
}

__device__ __forceinline__ short8 pack8(float4 a, float4 b) {
    short8 p;
    p[0] = (short)f2bf(a.x); p[1] = (short)f2bf(a.y);
    p[2] = (short)f2bf(a.z); p[3] = (short)f2bf(a.w);
    p[4] = (short)f2bf(b.x); p[5] = (short)f2bf(b.y);
    p[6] = (short)f2bf(b.z); p[7] = (short)f2bf(b.w);
    return p;
}

// XOR-swizzled LDS indexing (T2): linear rows, byte ^= (row&7)<<4.
__device__ __forceinline__ int swz64(int row, int bytecol) {   // 64-short rows
    return row * 64 + ((bytecol ^ ((row & 7) << 4)) >> 1);
}
__device__ __forceinline__ int swz256(int row, int bytecol) {  // 256-short rows
    return row * 256 + ((bytecol ^ ((row & 7) << 4)) >> 1);
}

// global -> LDS direct copy, 16B/lane. LDS dest = wave-uniform base + lane*16
// (m104); global src is per-lane. Source layouts are pre-swizzled so linear
// LDS writes yield the swz64 layout (rule #21: both-sides-or-neither).
__device__ __forceinline__ void async16(void* lds_uniform, const void* gsrc) {
    __builtin_amdgcn_global_load_lds(
        (const __attribute__((address_space(1))) unsigned int*)gsrc,
        (__attribute__((address_space(3))) unsigned int*)lds_uniform,
        16, 0, 0);
}

// ---------------------------------------------------------------------------
// Weight prep: wt[m][n][k'] = W_m[k][n] bf16, m in {Wq,Wk,Wv,Wo};
// swz!=0 stores k' = k ^ ((n&7)*8) within each 64-elem k-block.
// ---------------------------------------------------------------------------
__global__ __launch_bounds__(256) void wprep(
    const float* __restrict__ Wq, const float* __restrict__ Wk,
    const float* __restrict__ Wv, const float* __restrict__ Wo,
    unsigned short* __restrict__ wt, int swz)
{
    __shared__ float tile[64][65];
    const int bid = blockIdx.x;
    const int m = bid >> 6, tb = bid & 63;
    const int kr = (tb >> 3) << 6, nc = (tb & 7) << 6;
    const float* W = (m == 0) ? Wq : (m == 1) ? Wk : (m == 2) ? Wv : Wo;
    const int tid = threadIdx.x;
    for (int i = tid; i < 4096; i += 256)
        tile[i >> 6][i & 63] = W[(size_t)(kr + (i >> 6)) * 512 + nc + (i & 63)];
    __syncthreads();
    unsigned short* dst = wt + (size_t)m * 262144;
    for (int i = tid; i < 4096; i += 256) {
        const int n = nc + (i >> 6);
        const int e = i & 63;
        const int rsw = swz ? ((n & 7) * 8) : 0;
        dst[(size_t)n * 512 + kr + e] = f2bf(tile[e ^ rsw][i >> 6]);
    }
}

// ---------------------------------------------------------------------------
// X prep: xb[row][e] = bf16(hs[row][e ^ ((row&7)*8)])  (swizzle within each
// 64-elem k-block; e0 is 8-aligned and rsw is a multiple of 8, so XOR maps
// whole short8 groups).
// ---------------------------------------------------------------------------
__global__ __launch_bounds__(256) void xprep(
    const float* __restrict__ hs, unsigned short* __restrict__ xb)
{
    const long long total = 4194304;   // 65536*512/8
    for (long long g = (long long)blockIdx.x * 256 + threadIdx.x; g < total;
         g += (long long)gridDim.x * 256) {
        const int row = (int)(g >> 6);
        const int e0  = ((int)g & 63) * 8;
        const int src = e0 ^ ((row & 7) * 8);
        const float* s = hs + (size_t)row * 512 + src;
        const float4 f0 = *(const float4*)s;
        const float4 f1 = *(const float4*)(s + 4);
        *(short8*)(xb + (size_t)row * 512 + e0) = pack8(f0, f1);
    }
}

// ---------------------------------------------------------------------------
// m97-structure GEMM: C[M x nbcnt*128] = A[M][512] @ B^T, A/B bf16
// PRE-SWIZZLED, staged via global_load_lds(16B). 128x128 tile, BK=64,
// 256 thr = 4 waves (2x2), wave tile 64x64, 2-barrier K-loop.
// F32OUT=0: bf16 out into qkvb[3][65536][512] (col -> mat,cc).
// F32OUT=1: f32 out into of32[M][512].
// XCD-chunked bid remap (bijective: grid % 8 == 0).
// ---------------------------------------------------------------------------
template<int F32OUT>
__global__ __launch_bounds__(256) void gemm_glds(
    const unsigned short* __restrict__ A,
    const unsigned short* __restrict__ B,
    unsigned short* __restrict__ obf,
    float* __restrict__ of32,
    int nbcnt)
{
    __shared__ unsigned short As[128 * 64];   // 16 KB
    __shared__ unsigned short Bs[128 * 64];   // 16 KB

    const int orig  = blockIdx.x;
    const int chunk = gridDim.x >> 3;
    const int wg = (orig & 7) * chunk + (orig >> 3);
    const int mb = wg / nbcnt;
    const int nb = wg - mb * nbcnt;

    const int tid  = threadIdx.x;
    const int lane = tid & 63;
    const int w    = tid >> 6;
    const int l15  = lane & 15;
    const int hi4  = lane >> 4;
    const int wr   = w >> 1, wc = w & 1;

    f32x4 acc[4][4];
    #pragma unroll
    for (int mt = 0; mt < 4; ++mt)
        #pragma unroll
        for (int nt = 0; nt < 4; ++nt)
            acc[mt][nt] = (f32x4){0.f, 0.f, 0.f, 0.f};

    const char* __restrict__ Ab = (const char*)(A + (size_t)mb * 128 * 512);
    const char* __restrict__ Bb = (const char*)(B + (size_t)nb * 128 * 512);
    const int sbase = w * 4096;               // per-wave LDS byte base

    for (int kb = 0; kb < 512; kb += 64) {
        #pragma unroll
        for (int i = 0; i < 4; ++i) {
            const int sb = sbase + i * 1024;
            const int s  = sb + lane * 16;
            const int row = s >> 7, colb = s & 127;
            const size_t goff = (size_t)row * 1024 + kb * 2 + colb;
            async16(&As[sb >> 1], Ab + goff);
            async16(&Bs[sb >> 1], Bb + goff);
        }
        __syncthreads();
        #pragma unroll
        for (int ks = 0; ks < 2; ++ks) {
            short8 af[4];
            #pragma unroll
            for (int mt = 0; mt < 4; ++mt)
                af[mt] = *(const short8*)&As[swz64(wr * 64 + mt * 16 + l15,
                                                   ks * 64 + hi4 * 16)];
            __builtin_amdgcn_s_setprio(1);
            #pragma unroll
            for (int nt = 0; nt < 4; ++nt) {
                const short8 bf = *(const short8*)&Bs[swz64(wc * 64 + nt * 16 + l15,
                                                            ks * 64 + hi4 * 16)];
                #pragma unroll
                for (int mt = 0; mt < 4; ++mt)
                    acc[mt][nt] = MFMA16(af[mt], bf, acc[mt][nt]);
            }
            __builtin_amdgcn_s_setprio(0);
        }
        __syncthreads();
    }

    #pragma unroll
    for (int mt = 0; mt < 4; ++mt) {
        #pragma unroll
        for (int nt = 0; nt < 4; ++nt) {
            const int colt = nb * 128 + wc * 64 + nt * 16 + l15;
            #pragma unroll
            for (int r = 0; r < 4; ++r) {
                const int row = mb * 128 + wr * 64 + mt * 16 + hi4 * 4 + r;
                if (F32OUT) {
                    of32[(size_t)row * 512 + colt] = acc[mt][nt][r];
                } else {
                    const int mat = colt >> 9, cc = colt & 511;
                    obf[(size_t)mat * 33554432 + (size_t)row * 512 + cc] =
                        f2bf(acc[mt][nt][r]);
                }
            }
        }
    }
}

// ---------------------------------------------------------------------------
// QKV GEMM (middle path, round-6): reg-staged, swizzled LDS. Unchanged.
// ---------------------------------------------------------------------------
__global__ __launch_bounds__(1024, 4) void qkv_gemm2(
    const float* __restrict__ hs,
    const unsigned short* __restrict__ wt,
    unsigned short* __restrict__ qkvb)
{
    __shared__ unsigned short As[128 * 64];
    __shared__ unsigned short Bts[512 * 64];

    const int orig = blockIdx.x;
    const int wg = (orig & 7) * 192 + (orig >> 3);
    const int mb = wg / 3;
    const int nb = wg - mb * 3;

    const int tid  = threadIdx.x;
    const int lane = tid & 63;
    const int w    = tid >> 6;
    const int l15  = lane & 15;
    const int hi4  = lane >> 4;
    const int wr   = w >> 3;
    const int wc   = w & 7;

    f32x4 acc[4][4];
    #pragma unroll
    for (int mt = 0; mt < 4; ++mt)
        #pragma unroll
        for (int nt = 0; nt < 4; ++nt)
            acc[mt][nt] = (f32x4){0.f, 0.f, 0.f, 0.f};

    const int ar = tid >> 3, aq = tid & 7;
    const int bc = tid >> 1, bh = tid & 1;
    const float* __restrict__ asrc = hs + ((size_t)mb * 128 + ar) * 512 + aq * 8;
    const unsigned short* __restrict__ bsrc =
        wt + ((size_t)nb * 512 + bc) * 512 + bh * 32;

    float4 a0, a1;
    short8 b8[4];
    a0 = *(const float4*)asrc;
    a1 = *(const float4*)(asrc + 4);
    #pragma unroll
    for (int q = 0; q < 4; ++q) b8[q] = *(const short8*)(bsrc + q * 8);

    for (int kb = 0; kb < 512; kb += 64) {
        *(short8*)&As[swz64(ar, aq * 16)] = pack8(a0, a1);
        #pragma unroll
        for (int q = 0; q < 4; ++q)
            *(short8*)&Bts[swz64(bc, bh * 64 + q * 16)] = b8[q];
        __syncthreads();
        if (kb < 448) {
            const int kn = kb + 64;
            a0 = *(const float4*)(asrc + kn);
            a1 = *(const float4*)(asrc + kn + 4);
            #pragma unroll
            for (int q = 0; q < 4; ++q)
                b8[q] = *(const short8*)(bsrc + kn + q * 8);
        }
        #pragma unroll
        for (int ks = 0; ks < 2; ++ks) {
            short8 af[4];
            #pragma unroll
            for (int mt = 0; mt < 4; ++mt)
                af[mt] = *(const short8*)&As[swz64(wr * 64 + mt * 16 + l15,
                                                   ks * 64 + hi4 * 16)];
            __builtin_amdgcn_s_setprio(1);
            #pragma unroll
            for (int nt = 0; nt < 4; ++nt) {
                const short8 bf = *(const short8*)&Bts[swz64(wc * 64 + nt * 16 + l15,
                                                             ks * 64 + hi4 * 16)];
                #pragma unroll
                for (int mt = 0; mt < 4; ++mt)
                    acc[mt][nt] = MFMA16(af[mt], bf, acc[mt][nt]);
            }
            __builtin_amdgcn_s_setprio(0);
        }
        __syncthreads();
    }

    unsigned short* __restrict__ dst = qkvb + (size_t)nb * 33554432ull;
    #pragma unroll
    for (int mt = 0; mt < 4; ++mt) {
        #pragma unroll
        for (int nt = 0; nt < 4; ++nt) {
            const int col = wc * 64 + nt * 16 + l15;
            #pragma unroll
            for (int r = 0; r < 4; ++r) {
                const int row = mb * 128 + wr * 64 + mt * 16 + hi4 * 4 + r;
                dst[(size_t)row * 512 + col] = f2bf(acc[mt][nt][r]);
            }
        }
    }
}

// ---------------------------------------------------------------------------
// Attention: one block per (t,h). K (swz LDS) + V (transpose->Vt swz) staged
// from qkvb; Q frags straight to regs. Writes bf16 attn-out back into the Q
// region of qkvb (safe: each block overwrites exactly the rows it already
// read into registers). doswz!=0 pre-swizzles the stored columns so the
// output can feed gemm_glds directly.
// ---------------------------------------------------------------------------
__global__ __launch_bounds__(1024, 4) void attn_split(
    unsigned short* __restrict__ qkvb,
    const int* __restrict__ gid,
    int doswz)
{
    __shared__ unsigned short Ksh[256 * 64];
    __shared__ unsigned short Vt[64 * 256];
    __shared__ unsigned short Ps[256 * 64];
    __shared__ int sgid[256];
    __shared__ int glo[16], ghi[16];

    const int th = blockIdx.x;
    const int t = th >> 3, h = th & 7;
    const int tid  = threadIdx.x;
    const int lane = tid & 63;
    const int w    = tid >> 6;
    const int l15  = lane & 15;
    const int hi4  = lane >> 4;
    const int wrow = w << 4;

    if (tid < 16) { glo[tid] = 256; ghi[tid] = -1; }
    __syncthreads();
    if (tid < 256) {
        const int g = gid[tid];
        sgid[tid] = g;
        atomicMin(&glo[g], tid);
        atomicMax(&ghi[g], tid);
    }

    const size_t rowbase = (size_t)t * 256 * 512 + h * 64;
    unsigned short* __restrict__ qb = qkvb + rowbase;
    const unsigned short* __restrict__ kbp = qkvb + 33554432ull + rowbase;
    const unsigned short* __restrict__ vbp = qkvb + 67108864ull + rowbase;

    {
        const int kr = tid >> 2, kq = tid & 3;
        const short8 k0 = *(const short8*)(kbp + (size_t)kr * 512 + kq * 16);
        const short8 k1 = *(const short8*)(kbp + (size_t)kr * 512 + kq * 16 + 8);
        *(short8*)&Ksh[swz64(kr, kq * 32)]      = k0;
        *(short8*)&Ksh[swz64(kr, kq * 32 + 16)] = k1;
        const short8 v0 = *(const short8*)(vbp + (size_t)kr * 512 + kq * 16);
        const short8 v1 = *(const short8*)(vbp + (size_t)kr * 512 + kq * 16 + 8);
        *(short8*)&Ps[kr * 64 + kq * 16]     = v0;
        *(short8*)&Ps[kr * 64 + kq * 16 + 8] = v1;
    }
    short8 qf[2];
    #pragma unroll
    for (int ks = 0; ks < 2; ++ks)
        qf[ks] = *(const short8*)(qb + (size_t)(wrow + l15) * 512 + ks * 32 + hi4 * 8);
    __syncthreads();

    {
        const int d = tid & 63, jc = tid >> 6;
        short8 a, b;
        #pragma unroll
        for (int jj = 0; jj < 8; ++jj) a[jj] = Ps[(jc * 16 + jj) * 64 + d];
        #pragma unroll
        for (int jj = 0; jj < 8; ++jj) b[jj] = Ps[(jc * 16 + 8 + jj) * 64 + d];
        *(short8*)&Vt[swz256(d, jc * 32)]      = a;
        *(short8*)&Vt[swz256(d, jc * 32 + 16)] = b;
    }
    __syncthreads();

    int rg[4];
    #pragma unroll
    for (int r = 0; r < 4; ++r) rg[r] = sgid[wrow + hi4 * 4 + r];
    const int klo = glo[sgid[wrow]];
    const int khi = ghi[sgid[wrow + 15]];

    f32x4 o[4];
    float mrun[4], lrun[4];
    #pragma unroll
    for (int n = 0; n < 4; ++n) o[n] = (f32x4){0.f, 0.f, 0.f, 0.f};
    #pragma unroll
    for (int r = 0; r < 4; ++r) { mrun[r] = -3.0e38f; lrun[r] = 0.f; }

    for (int kc = klo & ~63; kc <= khi; kc += 64) {
        f32x4 sfr[4];
        __builtin_amdgcn_s_setprio(1);
        #pragma unroll
        for (int n = 0; n < 4; ++n) {
            const int krow = kc + n * 16 + l15;
            const short8 kf0 = *(const short8*)&Ksh[swz64(krow, hi4 * 16)];
            const short8 kf1 = *(const short8*)&Ksh[swz64(krow, 64 + hi4 * 16)];
            f32x4 z = (f32x4){0.f, 0.f, 0.f, 0.f};
            z = MFMA16(qf[0], kf0, z);
            z = MFMA16(qf[1], kf1, z);
            sfr[n] = z;
        }
        __builtin_amdgcn_s_setprio(0);
        int cg[4];
        #pragma unroll
        for (int n = 0; n < 4; ++n) cg[n] = sgid[kc + n * 16 + l15];

        #pragma unroll
        for (int r = 0; r < 4; ++r) {
            const int gr = rg[r];
            float sv[4];
            float smax = -3.0e38f;
            #pragma unroll
            for (int n = 0; n < 4; ++n) {
                float x = sfr[n][r] * 0.125f;
                x = (cg[n] == gr) ? x : -3.0e38f;
                sv[n] = x;
                smax = fmaxf(smax, x);
            }
            smax = fmaxf(smax, __shfl_xor(smax, 1));
            smax = fmaxf(smax, __shfl_xor(smax, 2));
            smax = fmaxf(smax, __shfl_xor(smax, 4));
            smax = fmaxf(smax, __shfl_xor(smax, 8));
            const float newm = fmaxf(mrun[r], smax);
            const float corr = __expf(mrun[r] - newm);
            float ps = 0.f;
            unsigned short pb[4];
            #pragma unroll
            for (int n = 0; n < 4; ++n) {
                const float p = (sv[n] > -1.0e38f) ? __expf(sv[n] - newm) : 0.f;
                ps += p;
                pb[n] = f2bf(p);
            }
            ps += __shfl_xor(ps, 1); ps += __shfl_xor(ps, 2);
            ps += __shfl_xor(ps, 4); ps += __shfl_xor(ps, 8);
            lrun[r] = lrun[r] * corr + ps;
            mrun[r] = newm;
            #pragma unroll
            for (int n = 0; n < 4; ++n) o[n][r] *= corr;
            const int prow = wrow + hi4 * 4 + r;
            #pragma unroll
            for (int n = 0; n < 4; ++n)
                Ps[swz64(prow, (n * 16 + l15) * 2)] = pb[n];
        }

        const short8 pa0 = *(const short8*)&Ps[swz64(wrow + l15, hi4 * 16)];
        const short8 pa1 = *(const short8*)&Ps[swz64(wrow + l15, 64 + hi4 * 16)];
        __builtin_amdgcn_s_setprio(1);
        #pragma unroll
        for (int n = 0; n < 4; ++n) {
            const short8 vb0 = *(const short8*)&Vt[swz256(n * 16 + l15, (kc + hi4 * 8) * 2)];
            const short8 vb1 = *(const short8*)&Vt[swz256(n * 16 + l15, (kc + 32 + hi4 * 8) * 2)];
            o[n] = MFMA16(pa0, vb0, o[n]);
            o[n] = MFMA16(pa1, vb1, o[n]);
        }
        __builtin_amdgcn_s_setprio(0);
    }

    #pragma unroll
    for (int r = 0; r < 4; ++r) {
        const int row = wrow + hi4 * 4 + r;
        const float inv = 1.0f / lrun[r];
        const int rsw = doswz ? ((row & 7) * 8) : 0;
        #pragma unroll
        for (int n = 0; n < 4; ++n) {
            const int cc = n * 16 + l15;
            qb[(size_t)row * 512 + (cc ^ rsw)] = f2bf(o[n][r] * inv);
        }
    }
}

// ---------------------------------------------------------------------------
// FALLBACK (ws tiny): round-4 fused QKV+attention, writes f32 attn-out to out.
// ---------------------------------------------------------------------------
__global__ __launch_bounds__(1024, 4) void qkv_attn_mfma(
    const float* __restrict__ hs,
    const int*   __restrict__ gid,
    const float* __restrict__ Wq, const float* __restrict__ Wk,
    const float* __restrict__ Wv,
    float*       __restrict__ out)
{
    __shared__ unsigned short Xs[256 * 64];
    __shared__ unsigned short Wsh[192 * 64];
    __shared__ unsigned short Ksh[256 * 64];
    __shared__ unsigned short Vt[64 * 256];
    __shared__ unsigned short XP[256 * 64];
    __shared__ int sgid[256];
    __shared__ int glo[16], ghi[16];

    const int bid = blockIdx.x;
    const int h   = (bid & 63) >> 3;
    const int t   = ((bid >> 6) << 3) + (bid & 7);

    const int tid  = threadIdx.x;
    const int lane = tid & 63;
    const int w    = tid >> 6;
    const int l15  = lane & 15;
    const int hi4  = lane >> 4;
    const int mg   = w & 3;
    const int ng   = w >> 2;

    if (tid < 16) { glo[tid] = 256; ghi[tid] = -1; }
    __syncthreads();
    if (tid < 256) {
        const int g = gid[tid];
        sgid[tid] = g;
        atomicMin(&glo[g], tid);
        atomicMax(&ghi[g], tid);
    }

    const float* __restrict__ Xbase = hs + (size_t)t * (256 * 512);

    const int xr = tid >> 2, xq = tid & 3;
    const bool doW = tid < 768;
    const int wc = tid >> 2;
    const int wq = tid & 3;
    const int wmat = wc >> 6, wcol = wc & 63;
    const float* __restrict__ wfsrc =
        (wmat == 0) ? Wq : (wmat == 1) ? Wk : Wv;

    f32x4 acc[4][3];
    #pragma unroll
    for (int mt = 0; mt < 4; ++mt)
        #pragma unroll
        for (int nt = 0; nt < 3; ++nt)
            acc[mt][nt] = (f32x4){0.f, 0.f, 0.f, 0.f};

    float4 xf[4];
    short8 w8[2];
    {
        const float* s = Xbase + (size_t)xr * 512 + xq * 16;
        xf[0] = *(const float4*)(s + 0);  xf[1] = *(const float4*)(s + 4);
        xf[2] = *(const float4*)(s + 8);  xf[3] = *(const float4*)(s + 12);
        if (doW) {
            #pragma unroll
            for (int b = 0; b < 2; ++b)
                #pragma unroll
                for (int j = 0; j < 8; ++j)
                    w8[b][j] = (short)f2bf(
                        wfsrc[(size_t)(wq * 16 + b * 8 + j) * 512 + h * 64 + wcol]);
        }
    }

    for (int kb = 0; kb < 512; kb += 64) {
        *(short8*)&Xs[swz64(xr, xq * 32 + 0)]  = pack8(xf[0], xf[1]);
        *(short8*)&Xs[swz64(xr, xq * 32 + 16)] = pack8(xf[2], xf[3]);
        if (doW) {
            *(short8*)&Wsh[swz64(wc, wq * 32 + 0)]  = w8[0];
            *(short8*)&Wsh[swz64(wc, wq * 32 + 16)] = w8[1];
        }
        __syncthreads();
        if (kb < 448) {
            const int kn = kb + 64;
            const float* s = Xbase + (size_t)xr * 512 + kn + xq * 16;
            xf[0] = *(const float4*)(s + 0);  xf[1] = *(const float4*)(s + 4);
            xf[2] = *(const float4*)(s + 8);  xf[3] = *(const float4*)(s + 12);
            if (doW) {
                #pragma unroll
                for (int b = 0; b < 2; ++b)
                    #pragma unroll
                    for (int j = 0; j < 8; ++j)
                        w8[b][j] = (short)f2bf(
                            wfsrc[(size_t)(kn + wq * 16 + b * 8 + j) * 512 + h * 64 + wcol]);
            }
        }
        #pragma unroll
        for (int ks = 0; ks < 2; ++ks) {
            short8 af[4];
            #pragma unroll
            for (int mt = 0; mt < 4; ++mt)
                af[mt] = *(const short8*)&Xs[swz64(mg * 64 + mt * 16 + l15,
                                                   ks * 64 + hi4 * 16)];
            __builtin_amdgcn_s_setprio(1);
            #pragma unroll
            for (int nt = 0; nt < 3; ++nt) {
                const short8 bf = *(const short8*)&Wsh[swz64(ng * 48 + nt * 16 + l15,
                                                             ks * 64 + hi4 * 16)];
                #pragma unroll
                for (int mt = 0; mt < 4; ++mt)
                    acc[mt][nt] = MFMA16(af[mt], bf, acc[mt][nt]);
            }
            __builtin_amdgcn_s_setprio(0);
        }
        __syncthreads();
    }

    #pragma unroll
    for (int nt = 0; nt < 3; ++nt) {
        const int c0 = (ng * 3 + nt) * 16;
        const int m  = c0 >> 6;
        const int d0 = c0 & 63;
        #pragma unroll
        for (int mt = 0; mt < 4; ++mt) {
            const int rowb = mg * 64 + mt * 16 + hi4 * 4;
            if (m == 0) {
                #pragma unroll
                for (int r = 0; r < 4; ++r)
                    XP[swz64(rowb + r, (d0 + l15) * 2)] = f2bf(acc[mt][nt][r]);
            } else if (m == 1) {
                #pragma unroll
                for (int r = 0; r < 4; ++r)
                    Ksh[swz64(rowb + r, (d0 + l15) * 2)] = f2bf(acc[mt][nt][r]);
            } else {
                short4v vv;
                #pragma unroll
                for (int r = 0; r < 4; ++r) vv[r] = (short)f2bf(acc[mt][nt][r]);
                *(short4v*)&Vt[swz256(d0 + l15, rowb * 2)] = vv;
            }
        }
    }
    __syncthreads();

    const int wrow = w << 4;
    int rg[4];
    #pragma unroll
    for (int r = 0; r < 4; ++r) rg[r] = sgid[wrow + hi4 * 4 + r];
    const int klo = glo[sgid[wrow]];
    const int khi = ghi[sgid[wrow + 15]];

    short8 qf[2];
    #pragma unroll
    for (int ks = 0; ks < 2; ++ks)
        qf[ks] = *(const short8*)&XP[swz64(wrow + l15, ks * 64 + hi4 * 16)];

    f32x4 o[4];
    float mrun[4], lrun[4];
    #pragma unroll
    for (int n = 0; n < 4; ++n) o[n] = (f32x4){0.f, 0.f, 0.f, 0.f};
    #pragma unroll
    for (int r = 0; r < 4; ++r) { mrun[r] = -3.0e38f; lrun[r] = 0.f; }

    for (int kc = klo & ~63; kc <= khi; kc += 64) {
        f32x4 sfr[4];
        __builtin_amdgcn_s_setprio(1);
        #pragma unroll
        for (int n = 0; n < 4; ++n) {
            const int krow = kc + n * 16 + l15;
            const short8 kf0 = *(const short8*)&Ksh[swz64(krow, hi4 * 16)];
            const short8 kf1 = *(const short8*)&Ksh[swz64(krow, 64 + hi4 * 16)];
            f32x4 z = (f32x4){0.f, 0.f, 0.f, 0.f};
            z = MFMA16(qf[0], kf0, z);
            z = MFMA16(qf[1], kf1, z);
            sfr[n] = z;
        }
        __builtin_amdgcn_s_setprio(0);
        int cg[4];
        #pragma unroll
        for (int n = 0; n < 4; ++n) cg[n] = sgid[kc + n * 16 + l15];

        #pragma unroll
        for (int r = 0; r < 4; ++r) {
            const int gr = rg[r];
            float sv[4];
            float smax = -3.0e38f;
            #pragma unroll
            for (int n = 0; n < 4; ++n) {
                float x = sfr[n][r] * 0.125f;
                x = (cg[n] == gr) ? x : -3.0e38f;
                sv[n] = x;
                smax = fmaxf(smax, x);
            }
            smax = fmaxf(smax, __shfl_xor(smax, 1));
            smax = fmaxf(smax, __shfl_xor(smax, 2));
            smax = fmaxf(smax, __shfl_xor(smax, 4));
            smax = fmaxf(smax, __shfl_xor(smax, 8));
            const float newm = fmaxf(mrun[r], smax);
            const float corr = __expf(mrun[r] - newm);
            float ps = 0.f;
            unsigned short pb[4];
            #pragma unroll
            for (int n = 0; n < 4; ++n) {
                const float p = (sv[n] > -1.0e38f) ? __expf(sv[n] - newm) : 0.f;
                ps += p;
                pb[n] = f2bf(p);
            }
            ps += __shfl_xor(ps, 1); ps += __shfl_xor(ps, 2);
            ps += __shfl_xor(ps, 4); ps += __shfl_xor(ps, 8);
            lrun[r] = lrun[r] * corr + ps;
            mrun[r] = newm;
            #pragma unroll
            for (int n = 0; n < 4; ++n) o[n][r] *= corr;
            const int prow = wrow + hi4 * 4 + r;
            #pragma unroll
            for (int n = 0; n < 4; ++n)
                XP[swz64(prow, (n * 16 + l15) * 2)] = pb[n];
        }

        const short8 pa0 = *(const short8*)&XP[swz64(wrow + l15, hi4 * 16)];
        const short8 pa1 = *(const short8*)&XP[swz64(wrow + l15, 64 + hi4 * 16)];
        __builtin_amdgcn_s_setprio(1);
        #pragma unroll
        for (int n = 0; n < 4; ++n) {
            const short8 vb0 = *(const short8*)&Vt[swz256(n * 16 + l15, (kc + hi4 * 8) * 2)];
            const short8 vb1 = *(const short8*)&Vt[swz256(n * 16 + l15, (kc + 32 + hi4 * 8) * 2)];
            o[n] = MFMA16(pa0, vb0, o[n]);
            o[n] = MFMA16(pa1, vb1, o[n]);
        }
        __builtin_amdgcn_s_setprio(0);
    }

    float* __restrict__ op = out + (size_t)t * (256 * 512) + h * 64;
    #pragma unroll
    for (int r = 0; r < 4; ++r) {
        const int row = wrow + hi4 * 4 + r;
        const float inv = 1.0f / lrun[r];
        #pragma unroll
        for (int n = 0; n < 4; ++n)
            op[(size_t)row * 512 + n * 16 + l15] = o[n][r] * inv;
    }
}

// ---------------------------------------------------------------------------
// O-projection (middle/fallback paths): A from bf16 abuf or f32 out in-place.
// ---------------------------------------------------------------------------
__global__ __launch_bounds__(1024, 4) void oproj_mfma(
    const float* __restrict__ Wo,
    const unsigned short* __restrict__ wot,
    const unsigned short* __restrict__ abuf,
    float* __restrict__ out)
{
    __shared__ unsigned short As[128 * 40];
    __shared__ unsigned short Bts[512 * 40];

    const int tid  = threadIdx.x;
    const int lane = tid & 63;
    const int w    = tid >> 6;
    const int l15  = lane & 15;
    const int hi4  = lane >> 4;
    const int wr   = w >> 2;
    const int wc   = w & 3;
    const size_t r0 = (size_t)blockIdx.x * 128;

    f32x4 acc[2][8];
    #pragma unroll
    for (int m = 0; m < 2; ++m)
        #pragma unroll
        for (int n = 0; n < 8; ++n)
            acc[m][n] = (f32x4){0.f, 0.f, 0.f, 0.f};

    const bool isA = tid < 512;
    const int bn = tid & 511;
    const int ai = bn >> 2, aq = bn & 3;

    float4 af0, af1;
    short8 a8;
    short8 b8[4];

    if (isA) {
        if (abuf) {
            a8 = *(const short8*)(abuf + (r0 + ai) * 512 + aq * 8);
        } else {
            const float* s = out + (r0 + ai) * 512 + aq * 8;
            af0 = *(const float4*)s; af1 = *(const float4*)(s + 4);
        }
    } else {
        if (wot) {
            #pragma unroll
            for (int q = 0; q < 4; ++q)
                b8[q] = *(const short8*)(wot + (size_t)bn * 512 + q * 8);
        } else {
            #pragma unroll
            for (int q = 0; q < 4; ++q)
                #pragma unroll
                for (int j = 0; j < 8; ++j)
                    b8[q][j] = (short)f2bf(Wo[(size_t)(q * 8 + j) * 512 + bn]);
        }
    }

    for (int kb = 0; kb < 512; kb += 32) {
        if (isA) *(short8*)&As[ai * 40 + aq * 8] = abuf ? a8 : pack8(af0, af1);
        else {
            #pragma unroll
            for (int q = 0; q < 4; ++q)
                *(short8*)&Bts[bn * 40 + q * 8] = b8[q];
        }
        __syncthreads();
        if (kb < 480) {
            const int kn = kb + 32;
            if (isA) {
                if (abuf) {
                    a8 = *(const short8*)(abuf + (r0 + ai) * 512 + kn + aq * 8);
                } else {
                    const float* s = out + (r0 + ai) * 512 + kn + aq * 8;
                    af0 = *(const float4*)s; af1 = *(const float4*)(s + 4);
                }
            } else {
                if (wot) {
                    #pragma unroll
                    for (int q = 0; q < 4; ++q)
                        b8[q] = *(const short8*)(wot + (size_t)bn * 512 + kn + q * 8);
                } else {
                    #pragma unroll
                    for (int q = 0; q < 4; ++q)
                        #pragma unroll
                        for (int j = 0; j < 8; ++j)
                            b8[q][j] = (short)f2bf(Wo[(size_t)(kn + q * 8 + j) * 512 + bn]);
                }
            }
        }
        short8 afr[2];
        #pragma unroll
        for (int m = 0; m < 2; ++m)
            afr[m] = *(const short8*)&As[(wr * 32 + m * 16 + l15) * 40 + hi4 * 8];
        __builtin_amdgcn_s_setprio(1);
        #pragma unroll
        for (int n = 0; n < 8; ++n) {
            const short8 bfr = *(const short8*)&Bts[(wc * 128 + n * 16 + l15) * 40 + hi4 * 8];
            #pragma unroll
            for (int m = 0; m < 2; ++m)
                acc[m][n] = MFMA16(afr[m], bfr, acc[m][n]);
        }
        __builtin_amdgcn_s_setprio(0);
        __syncthreads();
    }

    #pragma unroll
    for (int m = 0; m < 2; ++m)
        #pragma unroll
        for (int n = 0; n < 8; ++n)
            #pragma unroll
            for (int r = 0; r < 4; ++r)
                out[(r0 + wr * 32 + m * 16 + hi4 * 4 + r) * 512 + wc * 128 + n * 16 + l15] =
                    acc[m][n][r];
}

extern "C" void kernel_launch(void* const* d_in, const int* in_sizes, int n_in,
                              void* d_out, int out_size, void* d_ws, size_t ws_size,
                              hipStream_t stream) {
    const float* hs  = (const float*)d_in[0];
    const int*   gid = (const int*)  d_in[1];
    const float* Wq  = (const float*)d_in[2];
    const float* Wk  = (const float*)d_in[3];
    const float* Wv  = (const float*)d_in[4];
    const float* Wo  = (const float*)d_in[5];
    float* outp = (float*)d_out;

    const size_t WT_S  = 1048576;        // shorts: 4*512*512
    const size_t XB_S  = 33554432;       // 65536*512
    const size_t QKV_S = 100663296;      // 3*65536*512
    unsigned short* wt = (unsigned short*)d_ws;
    unsigned short* wot = wt + (size_t)3 * 262144;

    if (ws_size >= (WT_S + XB_S + QKV_S) * 2) {
        // fast path: pre-swizzled bf16 + global_load_lds GEMMs
        unsigned short* xb   = wt + WT_S;
        unsigned short* qkvb = xb + XB_S;
        wprep<<<256, 256, 0, stream>>>(Wq, Wk, Wv, Wo, wt, 1);
        xprep<<<2048, 256, 0, stream>>>(hs, xb);
        gemm_glds<0><<<6144, 256, 0, stream>>>(xb, wt, qkvb, nullptr, 12);
        attn_split<<<2048, 1024, 0, stream>>>(qkvb, gid, 1);
        gemm_glds<1><<<2048, 256, 0, stream>>>(qkvb, wot, nullptr, outp, 4);
    } else if (ws_size >= (WT_S + QKV_S) * 2) {
        // middle path: round-6 split (linear wt)
        unsigned short* qkvb = wt + WT_S;
        wprep<<<256, 256, 0, stream>>>(Wq, Wk, Wv, Wo, wt, 0);
        qkv_gemm2<<<1536, 1024, 0, stream>>>(hs, wt, qkvb);
        attn_split<<<2048, 1024, 0, stream>>>(qkvb, gid, 0);
        oproj_mfma<<<512, 1024, 0, stream>>>(Wo, wot, qkvb, outp);
    } else {
        // fallback: fused kernel, no workspace weights
        qkv_attn_mfma<<<2048, 1024, 0, stream>>>(hs, gid, Wq, Wk, Wv, outp);
        oproj_mfma<<<512, 1024, 0, stream>>>(Wo, nullptr, nullptr, outp);
    }
}